// Round 8
// baseline (55.182 us; speedup 1.0000x reference)
//
#include <hip/hip_runtime.h>

typedef __attribute__((ext_vector_type(4))) float f32x4;
typedef __attribute__((ext_vector_type(8))) short bf16x8;

#define NP 4096
#define IB 2

__device__ __forceinline__ unsigned short f2bf(float f) {
  unsigned int u = __float_as_uint(f);
  u = u + 0x7FFFu + ((u >> 16) & 1u);   // round-to-nearest-even
  return (unsigned short)(u >> 16);
}

// ---------------- pool (R5 version, byte-identical; launched TWICE this
// round as an instrumentation probe: T8 - T5 = pool_time + launch_gap) ------
// Block = IB peds, 256 threads: tx = which ped, ty = j-slot (stride 128).
// Per in-range pair: ONE u64 LDS atomic packing (qx+2^14)<<38 | (qy+2^14)<<12 | 1,
// fixed point scale 2^-11. Integer accumulation is order-independent.
// Self-pair lands in cell 136 with qx=qy=0, cnt 1; compensated in epilogue.
__global__ __launch_bounds__(256, 8) void pool_kernel(
    const float2* __restrict__ pos, const float2* __restrict__ past,
    unsigned short* __restrict__ gridws) {
  __shared__ unsigned long long acc[IB][256];
  const int tid = threadIdx.x;
  const int tx = tid & (IB - 1);
  const int ty = tid >> 1;          // 0..127
  const int ibase = blockIdx.x * IB;
  const int i = ibase + tx;

  for (int idx = tid; idx < IB * 256 * 2; idx += 256)
    ((unsigned int*)acc)[idx] = 0u;
  __syncthreads();

  const float2 pi = pos[i];
  const float2 qi = past[i];
  const float vix = pi.x - qi.x;
  const float viy = pi.y - qi.y;
  unsigned long long* accp = acc[tx];
  const float inv06 = 1.0f / 0.6f;

  auto process = [&](float2 pj, float2 qj) {
    float rx = pj.x - pi.x;
    float ry = pj.y - pi.y;
    float ax = __builtin_fmaf(rx, inv06, 8.0f);
    float ay = __builtin_fmaf(ry, inv06, 8.0f);
    bool unc = (fabsf(ax - rintf(ax)) < 1e-4f) |
               (fabsf(ay - rintf(ay)) < 1e-4f);
    float fx, fy;
    if (__any(unc)) {
      // exact IEEE fp32 division path to match numpy floor(rel/0.6 + 8)
      fx = floorf(rx / 0.6f + 8.0f);
      fy = floorf(ry / 0.6f + 8.0f);
    } else {
      fx = floorf(ax);
      fy = floorf(ay);
    }
    int ix = (int)fx;
    int iy = (int)fy;
    if (((unsigned)ix < 16u) & ((unsigned)iy < 16u)) {
      float rvx = (pj.x - qj.x) - vix;
      float rvy = (pj.y - qj.y) - viy;
      unsigned int qx = (unsigned int)((int)rintf(rvx * 2048.0f) + 16384);
      unsigned int qy = (unsigned int)((int)rintf(rvy * 2048.0f) + 16384);
      unsigned long long p = ((unsigned long long)qx << 38) |
                             ((unsigned long long)qy << 12) | 1ull;
      atomicAdd(&accp[(ix << 4) + iy], p);
    }
  };

  for (int jo = 0; jo < NP; jo += 512) {
    int j0 = jo + ty;
    float2 p0 = pos[j0];        float2 q0 = past[j0];
    float2 p1 = pos[j0 + 128];  float2 q1 = past[j0 + 128];
    float2 p2 = pos[j0 + 256];  float2 q2 = past[j0 + 256];
    float2 p3 = pos[j0 + 384];  float2 q3 = past[j0 + 384];
    process(p0, q0);
    process(p1, q1);
    process(p2, q2);
    process(p3, q3);
  }
  __syncthreads();

  // epilogue: decode u64, normalize (mean per cell), store bf16 [NP][512]
  const int cell = tid;  // 0..255
  const float selfc = (cell == 136) ? 1.0f : 0.0f;
#pragma unroll
  for (int il = 0; il < IB; ++il) {
    unsigned long long raw = acc[il][cell];
    unsigned int cnt = (unsigned int)(raw & 0xFFFull);
    int sxq = (int)((unsigned int)(raw >> 38)) - (int)(cnt << 14);
    int syq = (int)((unsigned int)((raw >> 12) & 0x3FFFFFFull)) - (int)(cnt << 14);
    float cn = (float)cnt - selfc;
    float d = fmaxf(cn, 1.0f);
    float sx = (float)sxq * (1.0f / 2048.0f);
    float sy = (float)syq * (1.0f / 2048.0f);
    unsigned int packed =
        ((unsigned int)f2bf(sy / d) << 16) | (unsigned int)f2bf(sx / d);
    *(unsigned int*)&gridws[(size_t)(ibase + il) * 512 + cell * 2] = packed;
  }
}

// ---------------- GEMM (R5 version, byte-identical) ----------------
// C[4096][256] = relu(A[4096][512](bf16) * W[256][512]^T + b), fp32 out.
// 64x64 tile per block, 4 waves in 2x2 quadrants, each wave 2x2 MFMA frags.
// LDS rows padded to 40 ushorts (80B): ds_read_b128 2-way conflict (free).
__global__ __launch_bounds__(256) void gemm_kernel(
    const unsigned short* __restrict__ A, const float* __restrict__ W,
    const float* __restrict__ bias, float* __restrict__ out) {
  __shared__ unsigned short As[64][40];
  __shared__ unsigned short Bs[64][40];
  const int tid = threadIdx.x;
  const int lane = tid & 63;
  const int wid = tid >> 6;
  const int wr = wid >> 1;
  const int wc = wid & 1;
  const int mbase = blockIdx.y * 64;
  const int nbase = blockIdx.x * 64;
  const int srow = tid >> 2;
  const int skq = tid & 3;

  f32x4 acc00 = {0.f, 0.f, 0.f, 0.f};
  f32x4 acc01 = {0.f, 0.f, 0.f, 0.f};
  f32x4 acc10 = {0.f, 0.f, 0.f, 0.f};
  f32x4 acc11 = {0.f, 0.f, 0.f, 0.f};

  const int lrow = lane & 15;
  const int lk = (lane >> 4) * 8;

  for (int kb = 0; kb < 512; kb += 32) {
    __syncthreads();
    *(bf16x8*)&As[srow][skq * 8] =
        *(const bf16x8*)&A[(size_t)(mbase + srow) * 512 + kb + skq * 8];
    const float* wp = &W[(size_t)(nbase + srow) * 512 + kb + skq * 8];
    float4 w0 = *(const float4*)wp;
    float4 w1 = *(const float4*)(wp + 4);
    bf16x8 bv;
    bv[0] = (short)f2bf(w0.x); bv[1] = (short)f2bf(w0.y);
    bv[2] = (short)f2bf(w0.z); bv[3] = (short)f2bf(w0.w);
    bv[4] = (short)f2bf(w1.x); bv[5] = (short)f2bf(w1.y);
    bv[6] = (short)f2bf(w1.z); bv[7] = (short)f2bf(w1.w);
    *(bf16x8*)&Bs[srow][skq * 8] = bv;
    __syncthreads();

    bf16x8 a0 = *(const bf16x8*)&As[wr * 32 + lrow][lk];
    bf16x8 a1 = *(const bf16x8*)&As[wr * 32 + 16 + lrow][lk];
    bf16x8 b0 = *(const bf16x8*)&Bs[wc * 32 + lrow][lk];
    bf16x8 b1 = *(const bf16x8*)&Bs[wc * 32 + 16 + lrow][lk];
    acc00 = __builtin_amdgcn_mfma_f32_16x16x32_bf16(a0, b0, acc00, 0, 0, 0);
    acc01 = __builtin_amdgcn_mfma_f32_16x16x32_bf16(a0, b1, acc01, 0, 0, 0);
    acc10 = __builtin_amdgcn_mfma_f32_16x16x32_bf16(a1, b0, acc10, 0, 0, 0);
    acc11 = __builtin_amdgcn_mfma_f32_16x16x32_bf16(a1, b1, acc11, 0, 0, 0);
  }

  const int row0 = mbase + wr * 32 + (lane >> 4) * 4;
  const int col0 = nbase + wc * 32 + lrow;
#pragma unroll
  for (int ni = 0; ni < 2; ++ni) {
    int col = col0 + ni * 16;
    float bv = bias[col];
    const f32x4* a0p = (ni == 0) ? &acc00 : &acc01;
    const f32x4* a1p = (ni == 0) ? &acc10 : &acc11;
#pragma unroll
    for (int q = 0; q < 4; ++q) {
      float v0 = (*a0p)[q] + bv;
      out[(size_t)(row0 + q) * 256 + col] = fmaxf(v0, 0.0f);
      float v1 = (*a1p)[q] + bv;
      out[(size_t)(row0 + 16 + q) * 256 + col] = fmaxf(v1, 0.0f);
    }
  }
}

extern "C" void kernel_launch(void* const* d_in, const int* in_sizes, int n_in,
                              void* d_out, int out_size, void* d_ws, size_t ws_size,
                              hipStream_t stream) {
  // inputs: 0=h (unused), 1=positions, 2=past_positions, 3=W_emb, 4=b_emb
  const float2* pos = (const float2*)d_in[1];
  const float2* past = (const float2*)d_in[2];
  const float* W = (const float*)d_in[3];
  const float* bias = (const float*)d_in[4];
  float* out = (float*)d_out;

  unsigned short* gridws = (unsigned short*)d_ws;  // 4 MB bf16 [NP][512]

  // Instrumentation: pool launched twice (idempotent). T8 - T5 = pool + gap.
  pool_kernel<<<NP / IB, 256, 0, stream>>>(pos, past, gridws);
  pool_kernel<<<NP / IB, 256, 0, stream>>>(pos, past, gridws);
  dim3 g(256 / 64, NP / 64);
  gemm_kernel<<<g, 256, 0, stream>>>(gridws, W, bias, out);
}

// Round 9
// 41.799 us; speedup vs baseline: 1.3202x; 1.3202x over previous
//
#include <hip/hip_runtime.h>

typedef __attribute__((ext_vector_type(4))) float f32x4;
typedef __attribute__((ext_vector_type(8))) short bf16x8;

#define NP 4096
#define IB 2

__device__ __forceinline__ unsigned short f2bf(float f) {
  unsigned int u = __float_as_uint(f);
  u = u + 0x7FFFu + ((u >> 16) & 1u);   // round-to-nearest-even
  return (unsigned short)(u >> 16);
}

// ---------------- pool (R5 u64 version) + inline W->bf16 conversion --------
// Block = IB peds, 256 threads: tx = which ped, ty = j-slot (stride 128).
// Per in-range pair: ONE u64 LDS atomic packing (qx+2^14)<<38 | (qy+2^14)<<12 | 1,
// fixed point scale 2^-11. Integer accumulation is order-independent.
// Self-pair lands in cell 136 with qx=qy=0, cnt 1; compensated in epilogue.
// Threads 0..7 of each block additionally convert 64 W elements fp32->bf16
// (2048 blocks x 64 = 131072 = 256x512), replacing the separate wconv launch.
__global__ __launch_bounds__(256, 8) void pool_kernel(
    const float2* __restrict__ pos, const float2* __restrict__ past,
    const float* __restrict__ W, unsigned short* __restrict__ Wb,
    unsigned short* __restrict__ gridws) {
  __shared__ unsigned long long acc[IB][256];
  const int tid = threadIdx.x;
  const int tx = tid & (IB - 1);
  const int ty = tid >> 1;          // 0..127
  const int ibase = blockIdx.x * IB;
  const int i = ibase + tx;

  // inline W conversion: 8 threads x 8 elements
  if (tid < 8) {
    int idx = blockIdx.x * 64 + tid * 8;
    float4 w0 = *(const float4*)&W[idx];
    float4 w1 = *(const float4*)&W[idx + 4];
    bf16x8 bv;
    bv[0] = (short)f2bf(w0.x); bv[1] = (short)f2bf(w0.y);
    bv[2] = (short)f2bf(w0.z); bv[3] = (short)f2bf(w0.w);
    bv[4] = (short)f2bf(w1.x); bv[5] = (short)f2bf(w1.y);
    bv[6] = (short)f2bf(w1.z); bv[7] = (short)f2bf(w1.w);
    *(bf16x8*)&Wb[idx] = bv;
  }

  for (int idx = tid; idx < IB * 256 * 2; idx += 256)
    ((unsigned int*)acc)[idx] = 0u;
  __syncthreads();

  const float2 pi = pos[i];
  const float2 qi = past[i];
  const float vix = pi.x - qi.x;
  const float viy = pi.y - qi.y;
  unsigned long long* accp = acc[tx];
  const float inv06 = 1.0f / 0.6f;

  auto process = [&](float2 pj, float2 qj) {
    float rx = pj.x - pi.x;
    float ry = pj.y - pi.y;
    float ax = __builtin_fmaf(rx, inv06, 8.0f);
    float ay = __builtin_fmaf(ry, inv06, 8.0f);
    bool unc = (fabsf(ax - rintf(ax)) < 1e-4f) |
               (fabsf(ay - rintf(ay)) < 1e-4f);
    float fx, fy;
    if (__any(unc)) {
      // exact IEEE fp32 division path to match numpy floor(rel/0.6 + 8)
      fx = floorf(rx / 0.6f + 8.0f);
      fy = floorf(ry / 0.6f + 8.0f);
    } else {
      fx = floorf(ax);
      fy = floorf(ay);
    }
    int ix = (int)fx;
    int iy = (int)fy;
    if (((unsigned)ix < 16u) & ((unsigned)iy < 16u)) {
      float rvx = (pj.x - qj.x) - vix;
      float rvy = (pj.y - qj.y) - viy;
      unsigned int qx = (unsigned int)((int)rintf(rvx * 2048.0f) + 16384);
      unsigned int qy = (unsigned int)((int)rintf(rvy * 2048.0f) + 16384);
      unsigned long long p = ((unsigned long long)qx << 38) |
                             ((unsigned long long)qy << 12) | 1ull;
      atomicAdd(&accp[(ix << 4) + iy], p);
    }
  };

  for (int jo = 0; jo < NP; jo += 512) {
    int j0 = jo + ty;
    float2 p0 = pos[j0];        float2 q0 = past[j0];
    float2 p1 = pos[j0 + 128];  float2 q1 = past[j0 + 128];
    float2 p2 = pos[j0 + 256];  float2 q2 = past[j0 + 256];
    float2 p3 = pos[j0 + 384];  float2 q3 = past[j0 + 384];
    process(p0, q0);
    process(p1, q1);
    process(p2, q2);
    process(p3, q3);
  }
  __syncthreads();

  // epilogue: decode u64, normalize (mean per cell), store bf16 [NP][512]
  const int cell = tid;  // 0..255
  const float selfc = (cell == 136) ? 1.0f : 0.0f;
#pragma unroll
  for (int il = 0; il < IB; ++il) {
    unsigned long long raw = acc[il][cell];
    unsigned int cnt = (unsigned int)(raw & 0xFFFull);
    int sxq = (int)((unsigned int)(raw >> 38)) - (int)(cnt << 14);
    int syq = (int)((unsigned int)((raw >> 12) & 0x3FFFFFFull)) - (int)(cnt << 14);
    float cn = (float)cnt - selfc;
    float d = fmaxf(cn, 1.0f);
    float sx = (float)sxq * (1.0f / 2048.0f);
    float sy = (float)syq * (1.0f / 2048.0f);
    unsigned int packed =
        ((unsigned int)f2bf(sy / d) << 16) | (unsigned int)f2bf(sx / d);
    *(unsigned int*)&gridws[(size_t)(ibase + il) * 512 + cell * 2] = packed;
  }
}

// ---------------- GEMM: single-round split-K over 8 waves ----------------
// C[4096][256] = relu(A[4096][512](bf16) @ Wb[256][512]^T + b), fp32 out.
// Block = 32x64 output tile, 8 waves; wave w owns K-slice [64w, 64w+64).
// Each wave: 12 independent 16B global fragment loads (issued once, no k-loop,
// no per-step barriers), 16 MFMAs, fp32 partial -> LDS. One barrier, then
// 512 threads reduce the 8 partials + bias + relu + float4 store.
// Exposed global latency paid ONCE per block; 512 blocks = 2/CU overlap it.
__global__ __launch_bounds__(512) void gemm_kernel(
    const unsigned short* __restrict__ A, const unsigned short* __restrict__ Wb,
    const float* __restrict__ bias, float* __restrict__ out) {
  __shared__ float red[8][32][65];   // pad 65: conflict-light write/read
  const int tid = threadIdx.x;
  const int lane = tid & 63;
  const int w = tid >> 6;            // 0..7 K-slice
  const int mbase = blockIdx.x * 32; // 128 m-blocks
  const int nbase = blockIdx.y * 64; // 4 n-blocks
  const int lrow = lane & 15;
  const int lk8 = (lane >> 4) * 8;
  const int k0 = w * 64;

  bf16x8 a[2][2], b[2][4];
#pragma unroll
  for (int ks = 0; ks < 2; ++ks) {
    const int kk = k0 + ks * 32 + lk8;
#pragma unroll
    for (int mf = 0; mf < 2; ++mf)
      a[ks][mf] = *(const bf16x8*)&A[(size_t)(mbase + mf * 16 + lrow) * 512 + kk];
#pragma unroll
    for (int nf = 0; nf < 4; ++nf)
      b[ks][nf] = *(const bf16x8*)&Wb[(size_t)(nbase + nf * 16 + lrow) * 512 + kk];
  }

  f32x4 acc[2][4] = {};
#pragma unroll
  for (int ks = 0; ks < 2; ++ks)
#pragma unroll
    for (int mf = 0; mf < 2; ++mf)
#pragma unroll
      for (int nf = 0; nf < 4; ++nf)
        acc[mf][nf] = __builtin_amdgcn_mfma_f32_16x16x32_bf16(
            a[ks][mf], b[ks][nf], acc[mf][nf], 0, 0, 0);

  // partials to LDS: D row = mf*16 + (lane>>4)*4 + q, col = nf*16 + (lane&15)
  const int rq = (lane >> 4) * 4;
#pragma unroll
  for (int mf = 0; mf < 2; ++mf)
#pragma unroll
    for (int nf = 0; nf < 4; ++nf)
#pragma unroll
      for (int q = 0; q < 4; ++q)
        red[w][mf * 16 + rq + q][nf * 16 + lrow] = acc[mf][nf][q];
  __syncthreads();

  // reduce 8 partials: thread -> (m = tid>>4, 4 consecutive n)
  const int m = tid >> 4;            // 0..31
  const int nq = (tid & 15) * 4;     // 0..60
  float s0 = 0.f, s1 = 0.f, s2 = 0.f, s3 = 0.f;
#pragma unroll
  for (int w2 = 0; w2 < 8; ++w2) {
    s0 += red[w2][m][nq + 0];
    s1 += red[w2][m][nq + 1];
    s2 += red[w2][m][nq + 2];
    s3 += red[w2][m][nq + 3];
  }
  const float4 bv = *(const float4*)&bias[nbase + nq];
  float4 o;
  o.x = fmaxf(s0 + bv.x, 0.0f);
  o.y = fmaxf(s1 + bv.y, 0.0f);
  o.z = fmaxf(s2 + bv.z, 0.0f);
  o.w = fmaxf(s3 + bv.w, 0.0f);
  *(float4*)&out[(size_t)(mbase + m) * 256 + nbase + nq] = o;
}

extern "C" void kernel_launch(void* const* d_in, const int* in_sizes, int n_in,
                              void* d_out, int out_size, void* d_ws, size_t ws_size,
                              hipStream_t stream) {
  // inputs: 0=h (unused), 1=positions, 2=past_positions, 3=W_emb, 4=b_emb
  const float2* pos = (const float2*)d_in[1];
  const float2* past = (const float2*)d_in[2];
  const float* W = (const float*)d_in[3];
  const float* bias = (const float*)d_in[4];
  float* out = (float*)d_out;

  unsigned short* gridws = (unsigned short*)d_ws;                         // 4 MB
  unsigned short* Wb = (unsigned short*)((char*)d_ws + 4 * 1024 * 1024);  // 256 KB

  pool_kernel<<<NP / IB, 256, 0, stream>>>(pos, past, W, Wb, gridws);
  // Instrumentation: gemm launched twice (idempotent). gemm = (T9 - pool - ovh)/2.
  dim3 g(NP / 32, 256 / 64);
  gemm_kernel<<<g, 512, 0, stream>>>(gridws, Wb, bias, out);
  gemm_kernel<<<g, 512, 0, stream>>>(gridws, Wb, bias, out);
}